// Round 4
// baseline (78.204 us; speedup 1.0000x reference)
//
#include <hip/hip_runtime.h>

// Problem constants
#define NQ 20
#define DIMQ (1 << NQ)          // 2^20
#define NB 16                   // BATCH
#define NT 4                    // N_TERMS
#define RBITS 15                // low bits untouched by gates
#define NCOL (1 << (RBITS + 4)) // 2^15 r-values * 16 batches = 524288 columns

// U table layout in ws/LDS: per (k,b): 36 floats (16 complex interleaved + 4 pad)
//   base = (k*16 + b) * 36 ; entry (i,j): re at base + (i*4+j)*2, im at +1
#define USTRIDE 36
#define UTOT (64 * USTRIDE)     // 2304 floats = 9216 B

// ---------------------------------------------------------------------------
// Kernel A: U[k,b] = exp(-i * H_k * t_{k,b}),  H_k = 0.5*(A + A^H), A = Hr + i Hi
// 256 threads: 64 tasks (k,b) x 4 rows. Scaling (2^-6) + 10-term Taylor + 6 squarings.
// ---------------------------------------------------------------------------
__global__ __launch_bounds__(256) void compute_u_kernel(
    const float* __restrict__ Hre, const float* __restrict__ Him,
    const float* __restrict__ tevo, float* __restrict__ uout) {
  __shared__ float er_s[64][4][4];
  __shared__ float ei_s[64][4][4];

  const int tid  = threadIdx.x;   // 0..255
  const int task = tid >> 2;      // 0..63
  const int row  = tid & 3;       // 0..3
  const int k    = task >> 4;     // 0..3
  const int b    = task & 15;     // 0..15

  float Ar[4][4], Ai[4][4];
#pragma unroll
  for (int i = 0; i < 4; i++) {
#pragma unroll
    for (int j = 0; j < 4; j++) {
      Ar[i][j] = Hre[k * 16 + i * 4 + j];
      Ai[i][j] = Him[k * 16 + i * 4 + j];
    }
  }
  const float t = tevo[k * NB + b];
  const float ts = t * (1.0f / 64.0f);  // scale 2^-6 folded in

  // G = -i * H * ts ; H = 0.5*(A + A^H)
  float Gr[4][4], Gi[4][4];
#pragma unroll
  for (int i = 0; i < 4; i++) {
#pragma unroll
    for (int j = 0; j < 4; j++) {
      const float hr = 0.5f * (Ar[i][j] + Ar[j][i]);
      const float hi = 0.5f * (Ai[i][j] - Ai[j][i]);
      Gr[i][j] = ts * hi;
      Gi[i][j] = -ts * hr;
    }
  }

  // Taylor: E = I + sum_{m=1..10} G^m/m!   (row `row` only; full G in regs)
  float Er[4], Ei[4], Tr[4], Ti[4];
#pragma unroll
  for (int j = 0; j < 4; j++) {
    Er[j] = (j == row) ? 1.0f : 0.0f;
    Ei[j] = 0.0f;
    Tr[j] = Er[j];
    Ti[j] = 0.0f;
  }
#pragma unroll
  for (int m = 1; m <= 10; m++) {
    const float inv = 1.0f / (float)m;
    float nr[4], ni[4];
#pragma unroll
    for (int j = 0; j < 4; j++) {
      float ar = 0.0f, ai = 0.0f;
#pragma unroll
      for (int p = 0; p < 4; p++) {
        ar += Tr[p] * Gr[p][j] - Ti[p] * Gi[p][j];
        ai += Tr[p] * Gi[p][j] + Ti[p] * Gr[p][j];
      }
      nr[j] = ar * inv;
      ni[j] = ai * inv;
    }
#pragma unroll
    for (int j = 0; j < 4; j++) {
      Tr[j] = nr[j]; Ti[j] = ni[j];
      Er[j] += nr[j]; Ei[j] += ni[j];
    }
  }

  // 6 squarings via LDS (uniform trip count -> barriers are safe)
  for (int q = 0; q < 6; q++) {
    __syncthreads();
#pragma unroll
    for (int j = 0; j < 4; j++) {
      er_s[task][row][j] = Er[j];
      ei_s[task][row][j] = Ei[j];
    }
    __syncthreads();
    float nr[4], ni[4];
#pragma unroll
    for (int j = 0; j < 4; j++) {
      float ar = 0.0f, ai = 0.0f;
#pragma unroll
      for (int p = 0; p < 4; p++) {
        ar += Er[p] * er_s[task][p][j] - Ei[p] * ei_s[task][p][j];
        ai += Er[p] * ei_s[task][p][j] + Ei[p] * er_s[task][p][j];
      }
      nr[j] = ar; ni[j] = ai;
    }
#pragma unroll
    for (int j = 0; j < 4; j++) { Er[j] = nr[j]; Ei[j] = ni[j]; }
  }

  // Store U rows: layout [k][b][16 complex interleaved], row stride 36 floats
  const int ubase = (k * 16 + b) * USTRIDE;
#pragma unroll
  for (int j = 0; j < 4; j++) {
    uout[ubase + (row * 4 + j) * 2]     = Er[j];
    uout[ubase + (row * 4 + j) * 2 + 1] = Ei[j];
  }
}

// ---------------------------------------------------------------------------
// Kernel B: two threads per column (r,b); each owns one 16-g half.
//   half = tid>>7 (wave-uniform), cIdx = tid&127, col = blockIdx*128 + cIdx.
// Gates k=1..3 act inside a half (g bits [3:0]); only k=0 (g bits [4:3])
// crosses halves -> other half's 16 complex loaded directly from global
// (L1/L2-hot, partner wave just fetched the lines) and consumed in k=0 only.
// Live set ~116 floats -> fits 128-VGPR budget at 4 waves/SIMD.
// ---------------------------------------------------------------------------
__global__ __launch_bounds__(256, 4) void apply_gates_kernel(
    const float* __restrict__ sre, const float* __restrict__ sim,
    const float* __restrict__ u, float* __restrict__ out) {
  __shared__ __align__(16) float ul[UTOT];
  const int tid = threadIdx.x;
  // stage U table (9 KiB) to LDS; UTOT = 9*256 exactly
#pragma unroll
  for (int q = 0; q < 9; q++) ul[tid + q * 256] = u[tid + q * 256];
  __syncthreads();

  const int half  = tid >> 7;       // 0 or 1, uniform per wave
  const int cIdx  = tid & 127;
  const int col   = blockIdx.x * 128 + cIdx;  // r*16 + b
  const int b     = cIdx & 15;
  const int gbase = half << 4;
  const int obase = (half ^ 1) << 4;

  // own half (s) and other half (t) state, 16 complex each
  float s_re[16], s_im[16], t_re[16], t_im[16];
#pragma unroll
  for (int q = 0; q < 16; q++) {
    const int off = col + ((gbase + q) << 19);
    s_re[q] = sre[off];
    s_im[q] = sim[off];
  }
#pragma unroll
  for (int q = 0; q < 16; q++) {
    const int off = col + ((obase + q) << 19);
    t_re[q] = sre[off];
    t_im[q] = sim[off];
  }

  float o_re[16], o_im[16];

  // ---- k = 0 (sh=3): cross-half term, initializes acc ----
  // output g = gbase|gq, gq = b3*8+l ; U row i = (g>>3)&3 = half*2 + b3
  // sources by j (g' = j<<3 | l): j=0 -> half0[l], j=1 -> half0[8+l],
  //                               j=2 -> half1[l], j=3 -> half1[8+l]
  {
    const float* ub0 = &ul[(0 * 16 + b) * USTRIDE];
    if (half == 0) {  // half0 data = s, half1 data = t, rows 0..1
#pragma unroll
      for (int b3 = 0; b3 < 2; b3++) {
        const float4 v0 = *(const float4*)(ub0 + (0 + b3) * 8);      // j=0,1
        const float4 v1 = *(const float4*)(ub0 + (0 + b3) * 8 + 4);  // j=2,3
#pragma unroll
        for (int l = 0; l < 8; l++) {
          const int gq = b3 * 8 + l;
          o_re[gq] = v0.x * s_re[l]     - v0.y * s_im[l]
                   + v0.z * s_re[8 + l] - v0.w * s_im[8 + l]
                   + v1.x * t_re[l]     - v1.y * t_im[l]
                   + v1.z * t_re[8 + l] - v1.w * t_im[8 + l];
          o_im[gq] = v0.x * s_im[l]     + v0.y * s_re[l]
                   + v0.z * s_im[8 + l] + v0.w * s_re[8 + l]
                   + v1.x * t_im[l]     + v1.y * t_re[l]
                   + v1.z * t_im[8 + l] + v1.w * t_re[8 + l];
        }
      }
    } else {          // half0 data = t, half1 data = s, rows 2..3
#pragma unroll
      for (int b3 = 0; b3 < 2; b3++) {
        const float4 v0 = *(const float4*)(ub0 + (2 + b3) * 8);      // j=0,1
        const float4 v1 = *(const float4*)(ub0 + (2 + b3) * 8 + 4);  // j=2,3
#pragma unroll
        for (int l = 0; l < 8; l++) {
          const int gq = b3 * 8 + l;
          o_re[gq] = v0.x * t_re[l]     - v0.y * t_im[l]
                   + v0.z * t_re[8 + l] - v0.w * t_im[8 + l]
                   + v1.x * s_re[l]     - v1.y * s_im[l]
                   + v1.z * s_re[8 + l] - v1.w * s_im[8 + l];
          o_im[gq] = v0.x * t_im[l]     + v0.y * t_re[l]
                   + v0.z * t_im[8 + l] + v0.w * t_re[8 + l]
                   + v1.x * s_im[l]     + v1.y * s_re[l]
                   + v1.z * s_im[8 + l] + v1.w * s_re[8 + l];
        }
      }
    }
  }

  // ---- k = 1..3: fully local to the half (bits [3:0] of g) ----
#pragma unroll
  for (int k = 1; k < 4; k++) {
    const int sh = 3 - k;  // 2, 1, 0
    const float* ub = &ul[(k * 16 + b) * USTRIDE];
#pragma unroll
    for (int i = 0; i < 4; i++) {
      const float4 v0 = *(const float4*)(ub + i * 8);      // j=0,1
      const float4 v1 = *(const float4*)(ub + i * 8 + 4);  // j=2,3
#pragma unroll
      for (int qq = 0; qq < 4; qq++) {
        const int low  = qq & ((1 << sh) - 1);
        const int high = (qq >> sh) << (sh + 2);
        const int gb   = high | low;           // gq with pair bits cleared
        const int gq   = gb | (i << sh);
        const int s0 = gb;
        const int s1 = gb | (1 << sh);
        const int s2 = gb | (2 << sh);
        const int s3 = gb | (3 << sh);
        o_re[gq] += v0.x * s_re[s0] - v0.y * s_im[s0]
                  + v0.z * s_re[s1] - v0.w * s_im[s1]
                  + v1.x * s_re[s2] - v1.y * s_im[s2]
                  + v1.z * s_re[s3] - v1.w * s_im[s3];
        o_im[gq] += v0.x * s_im[s0] + v0.y * s_re[s0]
                  + v0.z * s_im[s1] + v0.w * s_re[s1]
                  + v1.x * s_im[s2] + v1.y * s_re[s2]
                  + v1.z * s_im[s3] + v1.w * s_re[s3];
      }
    }
  }

#pragma unroll
  for (int q = 0; q < 16; q++) {
    const int off = col + ((gbase + q) << 19);
    __builtin_nontemporal_store(o_re[q], out + off);               // real
    __builtin_nontemporal_store(o_im[q], out + off + (1 << 24));   // imag
  }
}

extern "C" void kernel_launch(void* const* d_in, const int* in_sizes, int n_in,
                              void* d_out, int out_size, void* d_ws, size_t ws_size,
                              hipStream_t stream) {
  const float* Hre  = (const float*)d_in[0];
  const float* Him  = (const float*)d_in[1];
  const float* tevo = (const float*)d_in[2];
  const float* sre  = (const float*)d_in[3];
  const float* sim  = (const float*)d_in[4];
  float* out = (float*)d_out;
  float* uws = (float*)d_ws;  // UTOT floats = 9216 B

  compute_u_kernel<<<1, 256, 0, stream>>>(Hre, Him, tevo, uws);
  apply_gates_kernel<<<NCOL / 128, 256, 0, stream>>>(sre, sim, uws, out);
}

// Round 5
// 54.517 us; speedup vs baseline: 1.4345x; 1.4345x over previous
//
#include <hip/hip_runtime.h>

// Problem constants
#define NQ 20
#define DIMQ (1 << NQ)          // 2^20
#define NB 16                   // BATCH
#define NT 4                    // N_TERMS
#define RBITS 15                // low bits untouched by gates
#define NCOL (1 << (RBITS + 4)) // 2^15 r-values * 16 batches = 524288 columns

// U table layout in ws/LDS: per (k,b): 36 floats (16 complex interleaved + 4 pad)
//   base = (k*16 + b) * 36 ; entry (i,j): re at base + (i*4+j)*2, im at +1
//   36 floats = 144 B = 9*16 B -> every (k,b) base is 16B-aligned.
#define USTRIDE 36
#define UTOT (64 * USTRIDE)     // 2304 floats = 9216 B

// ---------------------------------------------------------------------------
// Kernel A: U[k,b] = exp(-i * H_k * t_{k,b}),  H_k = 0.5*(A + A^H), A = Hr + i Hi
// 256 threads: 64 tasks (k,b) x 4 rows. Scaling (2^-6) + 10-term Taylor + 6 squarings.
// ---------------------------------------------------------------------------
__global__ __launch_bounds__(256) void compute_u_kernel(
    const float* __restrict__ Hre, const float* __restrict__ Him,
    const float* __restrict__ tevo, float* __restrict__ uout) {
  __shared__ float er_s[64][4][4];
  __shared__ float ei_s[64][4][4];

  const int tid  = threadIdx.x;   // 0..255
  const int task = tid >> 2;      // 0..63
  const int row  = tid & 3;       // 0..3
  const int k    = task >> 4;     // 0..3
  const int b    = task & 15;     // 0..15

  float Ar[4][4], Ai[4][4];
#pragma unroll
  for (int i = 0; i < 4; i++) {
#pragma unroll
    for (int j = 0; j < 4; j++) {
      Ar[i][j] = Hre[k * 16 + i * 4 + j];
      Ai[i][j] = Him[k * 16 + i * 4 + j];
    }
  }
  const float t = tevo[k * NB + b];
  const float ts = t * (1.0f / 64.0f);  // scale 2^-6 folded in

  // G = -i * H * ts ; H = 0.5*(A + A^H)
  float Gr[4][4], Gi[4][4];
#pragma unroll
  for (int i = 0; i < 4; i++) {
#pragma unroll
    for (int j = 0; j < 4; j++) {
      const float hr = 0.5f * (Ar[i][j] + Ar[j][i]);
      const float hi = 0.5f * (Ai[i][j] - Ai[j][i]);
      Gr[i][j] = ts * hi;
      Gi[i][j] = -ts * hr;
    }
  }

  // Taylor: E = I + sum_{m=1..10} G^m/m!   (row `row` only; full G in regs)
  float Er[4], Ei[4], Tr[4], Ti[4];
#pragma unroll
  for (int j = 0; j < 4; j++) {
    Er[j] = (j == row) ? 1.0f : 0.0f;
    Ei[j] = 0.0f;
    Tr[j] = Er[j];
    Ti[j] = 0.0f;
  }
#pragma unroll
  for (int m = 1; m <= 10; m++) {
    const float inv = 1.0f / (float)m;
    float nr[4], ni[4];
#pragma unroll
    for (int j = 0; j < 4; j++) {
      float ar = 0.0f, ai = 0.0f;
#pragma unroll
      for (int p = 0; p < 4; p++) {
        ar += Tr[p] * Gr[p][j] - Ti[p] * Gi[p][j];
        ai += Tr[p] * Gi[p][j] + Ti[p] * Gr[p][j];
      }
      nr[j] = ar * inv;
      ni[j] = ai * inv;
    }
#pragma unroll
    for (int j = 0; j < 4; j++) {
      Tr[j] = nr[j]; Ti[j] = ni[j];
      Er[j] += nr[j]; Ei[j] += ni[j];
    }
  }

  // 6 squarings via LDS (uniform trip count -> barriers are safe)
  for (int q = 0; q < 6; q++) {
    __syncthreads();
#pragma unroll
    for (int j = 0; j < 4; j++) {
      er_s[task][row][j] = Er[j];
      ei_s[task][row][j] = Ei[j];
    }
    __syncthreads();
    float nr[4], ni[4];
#pragma unroll
    for (int j = 0; j < 4; j++) {
      float ar = 0.0f, ai = 0.0f;
#pragma unroll
      for (int p = 0; p < 4; p++) {
        ar += Er[p] * er_s[task][p][j] - Ei[p] * ei_s[task][p][j];
        ai += Er[p] * ei_s[task][p][j] + Ei[p] * er_s[task][p][j];
      }
      nr[j] = ar; ni[j] = ai;
    }
#pragma unroll
    for (int j = 0; j < 4; j++) { Er[j] = nr[j]; Ei[j] = ni[j]; }
  }

  // Store U rows: layout [k][b][16 complex interleaved], row stride 36 floats
  const int ubase = (k * 16 + b) * USTRIDE;
#pragma unroll
  for (int j = 0; j < 4; j++) {
    uout[ubase + (row * 4 + j) * 2]     = Er[j];
    uout[ubase + (row * 4 + j) * 2 + 1] = Ei[j];
  }
}

// ---------------------------------------------------------------------------
// Kernel B: two ADJACENT LANES per column (r,b); each owns one 16-g half.
//   half = tid&1, col = blockIdx*128 + (tid>>1), b = (tid>>1)&15.
// Gates k=1..3 act inside a half (g bits [3:0]). Gate k=0 (g bits [4:3])
// crosses halves: each thread computes its own-source partial for the
// partner's outputs and exchanges it with __shfl_xor(.,1) — no duplicate
// global reads, no LDS partial buffer, no extra barrier.
// Per-thread live set ~85 floats -> fits 128-VGPR budget, 4 waves/SIMD.
// Every state element is read exactly once across the grid.
// ---------------------------------------------------------------------------
__global__ __launch_bounds__(256, 4) void apply_gates_kernel(
    const float* __restrict__ sre, const float* __restrict__ sim,
    const float* __restrict__ u, float* __restrict__ out) {
  __shared__ __align__(16) float ul[UTOT];
  const int tid = threadIdx.x;
  // stage U table (9 KiB) to LDS; UTOT = 9*256 exactly
#pragma unroll
  for (int q = 0; q < 9; q++) ul[tid + q * 256] = u[tid + q * 256];
  __syncthreads();

  const int half  = tid & 1;                      // wave lanes alternate halves
  const int col   = blockIdx.x * 128 + (tid >> 1);  // r*16 + b
  const int b     = (tid >> 1) & 15;
  const int gbase = half << 4;

  // own half: 16 complex
  float s_re[16], s_im[16];
#pragma unroll
  for (int q = 0; q < 16; q++) {
    const int off = col + ((gbase + q) << 19);
    s_re[q] = sre[off];
    s_im[q] = sim[off];
  }

  float o_re[16], o_im[16];

  // ---- k = 0 (g bits [4:3]) : own term + shfl-exchanged cross term ----
  // own output g = half<<4 | b3<<3 | l : row i = 2*half + b3.
  // own sources s_re[l] (j=2*half), s_re[8+l] (j=2*half+1).
  // cross partial: contribution of MY sources (same j) to partner output
  // with row i' = 2*(half^1) + b3; partner adds the swapped value.
  {
    const float* ub0 = &ul[b * USTRIDE];  // k = 0 block
    const int h4 = half * 4;              // float offset of (j=2h) entry pair
#pragma unroll
    for (int b3 = 0; b3 < 2; b3++) {
      const float4 vo = *(const float4*)(ub0 + (half * 2 + b3) * 8 + h4);
      const float4 vc = *(const float4*)(ub0 + ((half ^ 1) * 2 + b3) * 8 + h4);
#pragma unroll
      for (int l = 0; l < 8; l++) {
        const int gq = b3 * 8 + l;
        o_re[gq] = vo.x * s_re[l]     - vo.y * s_im[l]
                 + vo.z * s_re[8 + l] - vo.w * s_im[8 + l];
        o_im[gq] = vo.x * s_im[l]     + vo.y * s_re[l]
                 + vo.z * s_im[8 + l] + vo.w * s_re[8 + l];
        float pr = vc.x * s_re[l]     - vc.y * s_im[l]
                 + vc.z * s_re[8 + l] - vc.w * s_im[8 + l];
        float pi = vc.x * s_im[l]     + vc.y * s_re[l]
                 + vc.z * s_im[8 + l] + vc.w * s_re[8 + l];
        o_re[gq] += __shfl_xor(pr, 1, 64);
        o_im[gq] += __shfl_xor(pi, 1, 64);
      }
    }
  }

  // ---- k = 1..3: fully local to the half (bits [3:0] of g) ----
#pragma unroll
  for (int k = 1; k < 4; k++) {
    const int sh = 3 - k;  // 2, 1, 0
    const float* ub = &ul[(k * 16 + b) * USTRIDE];
#pragma unroll
    for (int i = 0; i < 4; i++) {
      const float4 v0 = *(const float4*)(ub + i * 8);      // j=0,1
      const float4 v1 = *(const float4*)(ub + i * 8 + 4);  // j=2,3
#pragma unroll
      for (int qq = 0; qq < 4; qq++) {
        const int low  = qq & ((1 << sh) - 1);
        const int high = (qq >> sh) << (sh + 2);
        const int gb   = high | low;           // gq with pair bits cleared
        const int gq   = gb | (i << sh);
        const int s0 = gb;
        const int s1 = gb | (1 << sh);
        const int s2 = gb | (2 << sh);
        const int s3 = gb | (3 << sh);
        o_re[gq] += v0.x * s_re[s0] - v0.y * s_im[s0]
                  + v0.z * s_re[s1] - v0.w * s_im[s1]
                  + v1.x * s_re[s2] - v1.y * s_im[s2]
                  + v1.z * s_re[s3] - v1.w * s_im[s3];
        o_im[gq] += v0.x * s_im[s0] + v0.y * s_re[s0]
                  + v0.z * s_im[s1] + v0.w * s_re[s1]
                  + v1.x * s_im[s2] + v1.y * s_re[s2]
                  + v1.z * s_im[s3] + v1.w * s_re[s3];
      }
    }
  }

#pragma unroll
  for (int q = 0; q < 16; q++) {
    const int off = col + ((gbase + q) << 19);
    __builtin_nontemporal_store(o_re[q], out + off);               // real
    __builtin_nontemporal_store(o_im[q], out + off + (1 << 24));   // imag
  }
}

extern "C" void kernel_launch(void* const* d_in, const int* in_sizes, int n_in,
                              void* d_out, int out_size, void* d_ws, size_t ws_size,
                              hipStream_t stream) {
  const float* Hre  = (const float*)d_in[0];
  const float* Him  = (const float*)d_in[1];
  const float* tevo = (const float*)d_in[2];
  const float* sre  = (const float*)d_in[3];
  const float* sim  = (const float*)d_in[4];
  float* out = (float*)d_out;
  float* uws = (float*)d_ws;  // UTOT floats = 9216 B

  compute_u_kernel<<<1, 256, 0, stream>>>(Hre, Him, tevo, uws);
  apply_gates_kernel<<<NCOL / 128, 256, 0, stream>>>(sre, sim, uws, out);
}